// Round 5
// baseline (124.391 us; speedup 1.0000x reference)
//
#include <hip/hip_runtime.h>

// MedianFilter1D: x[16,64,16384] fp32, k=9, zero-pad 4 each side, lower median.
// Memory-bound: 128 MiB compulsory HBM traffic -> ~20.4us kernel floor @6.3TB/s.
// R5: back to R3's overlapping-load structure (R4's shuffle halo REGRESSED:
// ds_bpermute chains serialized load->shuffle->compute). 16 outputs/thread:
// 5 overlapping float4 loads (halo overlap absorbed by L1; unique HBM bytes
// unchanged), 4 nontemporal float4 stores. 0.3125 load-issues/output.

#define L_ROW  16384
#define L_MASK 16383

typedef float v4f __attribute__((ext_vector_type(4)));

__device__ __forceinline__ void s2(float &a, float &b) {
    float lo = fminf(a, b);
    float hi = fmaxf(a, b);
    a = lo; b = hi;
}

// Paeth's 19-CE median-of-9 network; returns the element at sorted pos 4.
__device__ __forceinline__ float med9(float p0, float p1, float p2, float p3,
                                      float p4, float p5, float p6, float p7,
                                      float p8) {
    s2(p1, p2); s2(p4, p5); s2(p7, p8);
    s2(p0, p1); s2(p3, p4); s2(p6, p7);
    s2(p1, p2); s2(p4, p5); s2(p7, p8);
    s2(p0, p3); s2(p5, p8); s2(p4, p7);
    s2(p3, p6); s2(p1, p4); s2(p2, p5);
    s2(p4, p7); s2(p4, p2); s2(p6, p4);
    s2(p4, p2);
    return p4;
}

__global__ __launch_bounds__(256, 4)
void MedianFilter1D_66924180406949_kernel(const float* __restrict__ x,
                                          float* __restrict__ y) {
    const int tid = blockIdx.x * 256 + threadIdx.x;   // 16-element group index
    const int v   = tid << 2;                         // base float4 index
    const int pos = tid << 4;                         // element index (flat)
    const int inrow = pos & L_MASK;                   // position within row

    const v4f* __restrict__ xv = (const v4f*)x;

    // Window w[0..23] = elements [pos-4 .. pos+19]
    v4f B0 = xv[v];
    v4f B1 = xv[v + 1];
    v4f B2 = xv[v + 2];
    v4f B3 = xv[v + 3];
    v4f A, C;
    if (inrow == 0) {                    // left row edge: zero pad
        A = (v4f){0.f, 0.f, 0.f, 0.f};
    } else {
        A = xv[v - 1];
    }
    if (inrow == (L_ROW - 16)) {         // right row edge: zero pad
        C = (v4f){0.f, 0.f, 0.f, 0.f};
    } else {
        C = xv[v + 4];
    }

    float w[24];
    w[0]  = A.x;  w[1]  = A.y;  w[2]  = A.z;  w[3]  = A.w;
    w[4]  = B0.x; w[5]  = B0.y; w[6]  = B0.z; w[7]  = B0.w;
    w[8]  = B1.x; w[9]  = B1.y; w[10] = B1.z; w[11] = B1.w;
    w[12] = B2.x; w[13] = B2.y; w[14] = B2.z; w[15] = B2.w;
    w[16] = B3.x; w[17] = B3.y; w[18] = B3.z; w[19] = B3.w;
    w[20] = C.x;  w[21] = C.y;  w[22] = C.z;  w[23] = C.w;

    v4f o0, o1, o2, o3;
    o0.x = med9(w[0],  w[1],  w[2],  w[3],  w[4],  w[5],  w[6],  w[7],  w[8]);
    o0.y = med9(w[1],  w[2],  w[3],  w[4],  w[5],  w[6],  w[7],  w[8],  w[9]);
    o0.z = med9(w[2],  w[3],  w[4],  w[5],  w[6],  w[7],  w[8],  w[9],  w[10]);
    o0.w = med9(w[3],  w[4],  w[5],  w[6],  w[7],  w[8],  w[9],  w[10], w[11]);
    o1.x = med9(w[4],  w[5],  w[6],  w[7],  w[8],  w[9],  w[10], w[11], w[12]);
    o1.y = med9(w[5],  w[6],  w[7],  w[8],  w[9],  w[10], w[11], w[12], w[13]);
    o1.z = med9(w[6],  w[7],  w[8],  w[9],  w[10], w[11], w[12], w[13], w[14]);
    o1.w = med9(w[7],  w[8],  w[9],  w[10], w[11], w[12], w[13], w[14], w[15]);
    o2.x = med9(w[8],  w[9],  w[10], w[11], w[12], w[13], w[14], w[15], w[16]);
    o2.y = med9(w[9],  w[10], w[11], w[12], w[13], w[14], w[15], w[16], w[17]);
    o2.z = med9(w[10], w[11], w[12], w[13], w[14], w[15], w[16], w[17], w[18]);
    o2.w = med9(w[11], w[12], w[13], w[14], w[15], w[16], w[17], w[18], w[19]);
    o3.x = med9(w[12], w[13], w[14], w[15], w[16], w[17], w[18], w[19], w[20]);
    o3.y = med9(w[13], w[14], w[15], w[16], w[17], w[18], w[19], w[20], w[21]);
    o3.z = med9(w[14], w[15], w[16], w[17], w[18], w[19], w[20], w[21], w[22]);
    o3.w = med9(w[15], w[16], w[17], w[18], w[19], w[20], w[21], w[22], w[23]);

    v4f* __restrict__ yv = (v4f*)y;
    __builtin_nontemporal_store(o0, &yv[v]);
    __builtin_nontemporal_store(o1, &yv[v + 1]);
    __builtin_nontemporal_store(o2, &yv[v + 2]);
    __builtin_nontemporal_store(o3, &yv[v + 3]);
}

extern "C" void kernel_launch(void* const* d_in, const int* in_sizes, int n_in,
                              void* d_out, int out_size, void* d_ws, size_t ws_size,
                              hipStream_t stream) {
    const float* x = (const float*)d_in[0];
    float* y = (float*)d_out;
    const int total = in_sizes[0];          // 16 * 64 * 16384 = 16777216
    const int threads = total / 16;         // one 16-element group per thread
    const int blocks = threads / 256;       // 4096 blocks
    MedianFilter1D_66924180406949_kernel<<<blocks, 256, 0, stream>>>(x, y);
}

// Round 6
// 108.515 us; speedup vs baseline: 1.1463x; 1.1463x over previous
//
#include <hip/hip_runtime.h>

// MedianFilter1D: x[16,64,16384] fp32, k=9, zero-pad 4 each side, lower median.
// Memory-bound: 128 MiB compulsory HBM traffic -> ~20.4us kernel floor @6.3TB/s.
// R6 = R3 (best measured: 108.5us total, kernel <42us). 8 outputs/thread,
// 3 overlapping aligned float4 loads (halo overlap absorbed by L1; unique HBM
// bytes unchanged), explicit scalars (NO indexed local array -- R5's float
// w[24] was demoted to scratch: VGPR=24, WRITE_SIZE 110MB vs 64MB output,
// kernel 61us), nontemporal stores.
// R4 (shuffle halo) regressed: ds_bpermute serializes load->shuffle->compute.

#define L_ROW  16384
#define L_MASK 16383

typedef float v4f __attribute__((ext_vector_type(4)));

__device__ __forceinline__ void s2(float &a, float &b) {
    float lo = fminf(a, b);
    float hi = fmaxf(a, b);
    a = lo; b = hi;
}

// Paeth's 19-CE median-of-9 network; returns the element at sorted pos 4.
__device__ __forceinline__ float med9(float p0, float p1, float p2, float p3,
                                      float p4, float p5, float p6, float p7,
                                      float p8) {
    s2(p1, p2); s2(p4, p5); s2(p7, p8);
    s2(p0, p1); s2(p3, p4); s2(p6, p7);
    s2(p1, p2); s2(p4, p5); s2(p7, p8);
    s2(p0, p3); s2(p5, p8); s2(p4, p7);
    s2(p3, p6); s2(p1, p4); s2(p2, p5);
    s2(p4, p7); s2(p4, p2); s2(p6, p4);
    s2(p4, p2);
    return p4;
}

__global__ __launch_bounds__(256, 4)
void MedianFilter1D_66924180406949_kernel(const float* __restrict__ x,
                                          float* __restrict__ y) {
    const int tid = blockIdx.x * 256 + threadIdx.x;   // 8-element group index
    const int v   = tid << 1;                         // base float4 index
    const int pos = tid << 3;                         // element index (flat)
    const int inrow = pos & L_MASK;                   // position within row

    const v4f* __restrict__ xv = (const v4f*)x;

    // Window w0..w15 = elements [pos-4 .. pos+11]
    v4f A, B0, B1, C;
    B0 = xv[v];
    B1 = xv[v + 1];
    if (inrow == 0) {                    // left row edge: zero pad
        A = (v4f){0.f, 0.f, 0.f, 0.f};
    } else {
        A = xv[v - 1];
    }
    if (inrow == (L_ROW - 8)) {          // right row edge: zero pad
        C = (v4f){0.f, 0.f, 0.f, 0.f};
    } else {
        C = xv[v + 2];
    }

    const float w0 = A.x,  w1 = A.y,  w2 = A.z,  w3 = A.w;
    const float w4 = B0.x, w5 = B0.y, w6 = B0.z, w7 = B0.w;
    const float w8 = B1.x, w9 = B1.y, w10 = B1.z, w11 = B1.w;
    const float w12 = C.x, w13 = C.y, w14 = C.z, w15 = C.w;

    v4f o0, o1;
    o0.x = med9(w0, w1, w2,  w3,  w4,  w5,  w6,  w7,  w8);
    o0.y = med9(w1, w2, w3,  w4,  w5,  w6,  w7,  w8,  w9);
    o0.z = med9(w2, w3, w4,  w5,  w6,  w7,  w8,  w9,  w10);
    o0.w = med9(w3, w4, w5,  w6,  w7,  w8,  w9,  w10, w11);
    o1.x = med9(w4, w5, w6,  w7,  w8,  w9,  w10, w11, w12);
    o1.y = med9(w5, w6, w7,  w8,  w9,  w10, w11, w12, w13);
    o1.z = med9(w6, w7, w8,  w9,  w10, w11, w12, w13, w14);
    o1.w = med9(w7, w8, w9,  w10, w11, w12, w13, w14, w15);

    v4f* __restrict__ yv = (v4f*)y;
    __builtin_nontemporal_store(o0, &yv[v]);
    __builtin_nontemporal_store(o1, &yv[v + 1]);
}

extern "C" void kernel_launch(void* const* d_in, const int* in_sizes, int n_in,
                              void* d_out, int out_size, void* d_ws, size_t ws_size,
                              hipStream_t stream) {
    const float* x = (const float*)d_in[0];
    float* y = (float*)d_out;
    const int total = in_sizes[0];          // 16 * 64 * 16384 = 16777216
    const int threads = total / 8;          // one 8-element group per thread
    const int blocks = threads / 256;       // 8192 blocks
    MedianFilter1D_66924180406949_kernel<<<blocks, 256, 0, stream>>>(x, y);
}